// Round 1
// baseline (212.668 us; speedup 1.0000x reference)
//
#include <hip/hip_runtime.h>
#include <math.h>

// Problem sizes
constexpr int NB = 2048;  // batch
constexpr int ND = 32;    // data dim (x has ND+1 cols, last replaced by t)
constexpr int NH = 512;   // hidden
constexpr int ST = 8;     // samples per block in the big GEMV kernels

// ---------------------------------------------------------------------------
// Kernel 0: M[j,k] = W2[j,k] * G[k,j], G[k,j] = sum_{i<32} W3[k,i]*W1[i,j]
// Grid: NH*NH/256 blocks x 256 threads. Within a block j is constant,
// k varies with lane -> W2/M accesses coalesced; W1[i*NH+j] is broadcast.
// ---------------------------------------------------------------------------
__global__ __launch_bounds__(256) void k_precompute_M(
    const float* __restrict__ W1, const float* __restrict__ W2,
    const float* __restrict__ W3, float* __restrict__ M) {
  int g = blockIdx.x * 256 + threadIdx.x;  // 0 .. NH*NH-1
  int j = g >> 9;        // row of W2
  int k = g & (NH - 1);  // col of W2
  float acc = 0.f;
#pragma unroll
  for (int i = 0; i < ND; ++i)
    acc += W3[k * ND + i] * W1[i * NH + j];
  M[g] = W2[g] * acc;
}

// ---------------------------------------------------------------------------
// Kernel 1: H1[s,k] = tanh( sum_{i<32} x[s,i]*W1[i,k] + t*W1[32,k] + b1[k] )
// One thread per (s,k). k contiguous in lanes -> W1 coalesced, x broadcast.
// ---------------------------------------------------------------------------
__global__ __launch_bounds__(256) void k_h1(
    const float* __restrict__ x, const float* __restrict__ t,
    const float* __restrict__ W1, const float* __restrict__ b1,
    float* __restrict__ H1g) {
  int g = blockIdx.x * 256 + threadIdx.x;  // 0 .. NB*NH-1
  int s = g >> 9;
  int k = g & (NH - 1);
  const float* xs = x + s * (ND + 1);
  float acc = b1[k];
#pragma unroll
  for (int i = 0; i < ND; ++i)
    acc += xs[i] * W1[i * NH + k];
  acc += t[0] * W1[ND * NH + k];
  H1g[g] = tanhf(acc);
}

// ---------------------------------------------------------------------------
// Kernel 2: H2[s,k] = tanh( H1[s,:] @ W2[:,k] + b2[k] )
// Block: ST samples x full 512 cols. 256 threads each own cols {t, t+256}
// for all ST samples (16 accumulators). H1 tile staged in LDS, read as
// float4 broadcasts; W2 rows streamed coalesced from L2.
// ---------------------------------------------------------------------------
__global__ __launch_bounds__(256) void k_h2(
    const float* __restrict__ H1g, const float* __restrict__ W2,
    const float* __restrict__ b2, float* __restrict__ H2g) {
  __shared__ float h1s[ST * NH];
  int s0 = blockIdx.x * ST;
  int tid = threadIdx.x;
  for (int idx = tid; idx < ST * NH; idx += 256)
    h1s[idx] = H1g[s0 * NH + idx];
  __syncthreads();

  int k0 = tid, k1 = tid + 256;
  float acc0[ST], acc1[ST];
  float bb0 = b2[k0], bb1 = b2[k1];
#pragma unroll
  for (int s = 0; s < ST; ++s) { acc0[s] = bb0; acc1[s] = bb1; }

  for (int j = 0; j < NH; j += 4) {
    float w00 = W2[(j + 0) * NH + k0], w01 = W2[(j + 0) * NH + k1];
    float w10 = W2[(j + 1) * NH + k0], w11 = W2[(j + 1) * NH + k1];
    float w20 = W2[(j + 2) * NH + k0], w21 = W2[(j + 2) * NH + k1];
    float w30 = W2[(j + 3) * NH + k0], w31 = W2[(j + 3) * NH + k1];
#pragma unroll
    for (int s = 0; s < ST; ++s) {
      float4 h = *(const float4*)&h1s[s * NH + j];
      acc0[s] += h.x * w00; acc1[s] += h.x * w01;
      acc0[s] += h.y * w10; acc1[s] += h.y * w11;
      acc0[s] += h.z * w20; acc1[s] += h.z * w21;
      acc0[s] += h.w * w30; acc1[s] += h.w * w31;
    }
  }
#pragma unroll
  for (int s = 0; s < ST; ++s) {
    H2g[(s0 + s) * NH + k0] = tanhf(acc0[s]);
    H2g[(s0 + s) * NH + k1] = tanhf(acc1[s]);
  }
}

// ---------------------------------------------------------------------------
// Kernel 3: out[s, i<32] = H2[s,:] @ W3[:,i] + b3[i]
// One thread per (s,i); wave = 2 samples x 32 cols. W3 rows are 128B, cached.
// ---------------------------------------------------------------------------
__global__ __launch_bounds__(256) void k_dx(
    const float* __restrict__ H2g, const float* __restrict__ W3,
    const float* __restrict__ b3, float* __restrict__ out) {
  int g = blockIdx.x * 256 + threadIdx.x;  // 0 .. NB*ND-1
  int s = g >> 5;
  int i = g & (ND - 1);
  const float* h2 = H2g + s * NH;
  float acc = b3[i];
  for (int k = 0; k < NH; k += 4) {
    acc += h2[k + 0] * W3[(k + 0) * ND + i];
    acc += h2[k + 1] * W3[(k + 1) * ND + i];
    acc += h2[k + 2] * W3[(k + 2) * ND + i];
    acc += h2[k + 3] * W3[(k + 3) * ND + i];
  }
  out[s * (ND + 1) + i] = acc;
}

// ---------------------------------------------------------------------------
// Kernel 4: div[s] = sum_k (1-H2[s,k]^2) * sum_j (1-H1[s,j]^2) * M[j,k]
// Same structure as k_h2 with A = D1 staged in LDS, B = M; epilogue fuses
// the d2 weighting and a block-wide reduction to a single scalar per sample.
// ---------------------------------------------------------------------------
__global__ __launch_bounds__(256) void k_div(
    const float* __restrict__ H1g, const float* __restrict__ H2g,
    const float* __restrict__ Mg, float* __restrict__ out) {
  __shared__ float d1s[ST * NH];
  __shared__ float red[4][ST];
  int s0 = blockIdx.x * ST;
  int tid = threadIdx.x;
  for (int idx = tid; idx < ST * NH; idx += 256) {
    float h = H1g[s0 * NH + idx];
    d1s[idx] = 1.f - h * h;
  }
  __syncthreads();

  int k0 = tid, k1 = tid + 256;
  float acc0[ST], acc1[ST];
#pragma unroll
  for (int s = 0; s < ST; ++s) { acc0[s] = 0.f; acc1[s] = 0.f; }

  for (int j = 0; j < NH; j += 4) {
    float w00 = Mg[(j + 0) * NH + k0], w01 = Mg[(j + 0) * NH + k1];
    float w10 = Mg[(j + 1) * NH + k0], w11 = Mg[(j + 1) * NH + k1];
    float w20 = Mg[(j + 2) * NH + k0], w21 = Mg[(j + 2) * NH + k1];
    float w30 = Mg[(j + 3) * NH + k0], w31 = Mg[(j + 3) * NH + k1];
#pragma unroll
    for (int s = 0; s < ST; ++s) {
      float4 h = *(const float4*)&d1s[s * NH + j];
      acc0[s] += h.x * w00; acc1[s] += h.x * w01;
      acc0[s] += h.y * w10; acc1[s] += h.y * w11;
      acc0[s] += h.z * w20; acc1[s] += h.z * w21;
      acc0[s] += h.w * w30; acc1[s] += h.w * w31;
    }
  }

  float partial[ST];
#pragma unroll
  for (int s = 0; s < ST; ++s) {
    float h20 = H2g[(s0 + s) * NH + k0];
    float h21 = H2g[(s0 + s) * NH + k1];
    partial[s] = acc0[s] * (1.f - h20 * h20) + acc1[s] * (1.f - h21 * h21);
  }

  int lane = tid & 63, wave = tid >> 6;
#pragma unroll
  for (int s = 0; s < ST; ++s) {
    float v = partial[s];
    for (int off = 32; off > 0; off >>= 1) v += __shfl_down(v, off);
    if (lane == 0) red[wave][s] = v;
  }
  __syncthreads();
  if (tid < ST) {
    float v = red[0][tid] + red[1][tid] + red[2][tid] + red[3][tid];
    out[(s0 + tid) * (ND + 1) + ND] = v;
  }
}

// ---------------------------------------------------------------------------
extern "C" void kernel_launch(void* const* d_in, const int* in_sizes, int n_in,
                              void* d_out, int out_size, void* d_ws, size_t ws_size,
                              hipStream_t stream) {
  const float* t  = (const float*)d_in[0];
  const float* x  = (const float*)d_in[1];
  const float* W1 = (const float*)d_in[2];
  const float* b1 = (const float*)d_in[3];
  const float* W2 = (const float*)d_in[4];
  const float* b2 = (const float*)d_in[5];
  const float* W3 = (const float*)d_in[6];
  const float* b3 = (const float*)d_in[7];
  float* out = (float*)d_out;

  float* M   = (float*)d_ws;          // NH*NH
  float* H1g = M + NH * NH;           // NB*NH
  float* H2g = H1g + NB * NH;         // NB*NH

  k_precompute_M<<<NH * NH / 256, 256, 0, stream>>>(W1, W2, W3, M);
  k_h1<<<NB * NH / 256, 256, 0, stream>>>(x, t, W1, b1, H1g);
  k_h2<<<NB / ST, 256, 0, stream>>>(H1g, W2, b2, H2g);
  k_dx<<<NB * ND / 256, 256, 0, stream>>>(H2g, W3, b3, out);
  k_div<<<NB / ST, 256, 0, stream>>>(H1g, H2g, M, out);
}

// Round 2
// 121.981 us; speedup vs baseline: 1.7435x; 1.7435x over previous
//
#include <hip/hip_runtime.h>
#include <math.h>

// Problem sizes
constexpr int NB = 2048;  // batch
constexpr int ND = 32;    // data dim (x has ND+1 cols, last is t)
constexpr int NH = 512;   // hidden
constexpr int NKI = NH / 32;  // k-iterations of 32 per MFMA chain = 16
constexpr int NRT = NB / 16;  // row tiles = 128
constexpr int NCT = NH / 16;  // col tiles = 32

typedef __bf16 bf16x8 __attribute__((ext_vector_type(8)));
typedef float floatx4 __attribute__((ext_vector_type(4)));

__device__ inline float fast_tanh(float x) {
  float e = __expf(2.f * x);
  return 1.f - 2.f / (e + 1.f);
}

// Fragment-layout pack index: elem = ((tile*NKI + ki)*64 + lane)*8 + j
// A-frag (16x16x32): row m = tile*16 + (lane&15), k = ki*32 + (lane>>4)*8 + j
// B-frag:            col n = tile*16 + (lane&15), k = ki*32 + (lane>>4)*8 + j
// C/D frag:          col = lane&15, row = (lane>>4)*4 + reg   [m89-verified]

// ---------------------------------------------------------------------------
// Kernel 0: build W2pack (bf16 B-frag of W2) and Mpack (bf16 B-frag of M),
// where M[j,k] = W2[j,k] * G[k,j], G[k,j] = sum_{i<32} W3[k,i]*W1[i,j].
// Blocks 0..127 -> W2pack, 128..255 -> Mpack. 32*16*64 = 32768 threads each.
// ---------------------------------------------------------------------------
__global__ __launch_bounds__(256) void k_prep(
    const float* __restrict__ W1, const float* __restrict__ W2,
    const float* __restrict__ W3, __bf16* __restrict__ W2p,
    __bf16* __restrict__ Mp) {
  bool doM = blockIdx.x >= 128;
  int gid = (blockIdx.x & 127) * 256 + threadIdx.x;  // 0..32767
  int lane = gid & 63;
  int ki = (gid >> 6) & (NKI - 1);
  int ct = gid >> 10;                 // 0..31
  int n = ct * 16 + (lane & 15);      // output column
  int k0 = ki * 32 + (lane >> 4) * 8; // k-range start (8 contiguous)
  long off = (long)gid * 8;

  if (!doM) {
    __bf16 v[8];
#pragma unroll
    for (int j = 0; j < 8; ++j) v[j] = (__bf16)W2[(k0 + j) * NH + n];
    *(bf16x8*)(W2p + off) = *(bf16x8*)v;
  } else {
    // Mp column n (2nd hidden idx), k = first hidden idx (rows of W2)
    float acc[8];
#pragma unroll
    for (int j = 0; j < 8; ++j) acc[j] = 0.f;
    for (int i = 0; i < ND; ++i) {
      float w3 = W3[n * ND + i];
      float4 u = *(const float4*)&W1[i * NH + k0];
      float4 v = *(const float4*)&W1[i * NH + k0 + 4];
      acc[0] += w3 * u.x; acc[1] += w3 * u.y;
      acc[2] += w3 * u.z; acc[3] += w3 * u.w;
      acc[4] += w3 * v.x; acc[5] += w3 * v.y;
      acc[6] += w3 * v.z; acc[7] += w3 * v.w;
    }
    __bf16 v[8];
#pragma unroll
    for (int j = 0; j < 8; ++j)
      v[j] = (__bf16)(W2[(k0 + j) * NH + n] * acc[j]);
    *(bf16x8*)(Mp + off) = *(bf16x8*)v;
  }
}

// ---------------------------------------------------------------------------
// Kernel 1: H1 = tanh([x;t] @ W1 + b1), written directly as bf16 A-frag pack,
// plus D1 = 1 - H1^2 as a second A-frag pack. Thread = (rt, ki, lane),
// computes 8 k-values for its row. 128*16*64 = 131072 threads.
// ---------------------------------------------------------------------------
__global__ __launch_bounds__(256) void k_h1(
    const float* __restrict__ x, const float* __restrict__ t,
    const float* __restrict__ W1, const float* __restrict__ b1,
    __bf16* __restrict__ H1p, __bf16* __restrict__ D1p) {
  int gid = blockIdx.x * 256 + threadIdx.x;  // 0..131071
  int lane = gid & 63;
  int ki = (gid >> 6) & (NKI - 1);
  int rt = gid >> 10;                  // 0..127
  int m = rt * 16 + (lane & 15);       // sample row
  int k0 = ki * 32 + (lane >> 4) * 8;  // 8 contiguous k
  const float* xs = x + m * (ND + 1);

  float acc[8];
#pragma unroll
  for (int j = 0; j < 8; ++j) acc[j] = b1[k0 + j];
#pragma unroll
  for (int i = 0; i < ND; ++i) {
    float xv = xs[i];
    float4 u = *(const float4*)&W1[i * NH + k0];
    float4 v = *(const float4*)&W1[i * NH + k0 + 4];
    acc[0] += xv * u.x; acc[1] += xv * u.y;
    acc[2] += xv * u.z; acc[3] += xv * u.w;
    acc[4] += xv * v.x; acc[5] += xv * v.y;
    acc[6] += xv * v.z; acc[7] += xv * v.w;
  }
  {
    float tv = t[0];
    float4 u = *(const float4*)&W1[ND * NH + k0];
    float4 v = *(const float4*)&W1[ND * NH + k0 + 4];
    acc[0] += tv * u.x; acc[1] += tv * u.y;
    acc[2] += tv * u.z; acc[3] += tv * u.w;
    acc[4] += tv * v.x; acc[5] += tv * v.y;
    acc[6] += tv * v.z; acc[7] += tv * v.w;
  }
  __bf16 hv[8], dv[8];
#pragma unroll
  for (int j = 0; j < 8; ++j) {
    float h = fast_tanh(acc[j]);
    hv[j] = (__bf16)h;
    dv[j] = (__bf16)(1.f - h * h);
  }
  long off = (long)gid * 8;
  *(bf16x8*)(H1p + off) = *(bf16x8*)hv;
  *(bf16x8*)(D1p + off) = *(bf16x8*)dv;
}

// ---------------------------------------------------------------------------
// Kernel 2: H2 = tanh(H1 @ W2 + b2), row-major fp32 output.
// MFMA GEMM: each wave owns a 2x2 group of 16x16 tiles; operands streamed
// straight from packed fragments (no LDS). 1024 waves = 256 blocks.
// ---------------------------------------------------------------------------
__global__ __launch_bounds__(256) void k_h2(
    const __bf16* __restrict__ Ap, const __bf16* __restrict__ Bp,
    const float* __restrict__ b2, float* __restrict__ H2) {
  int gw = blockIdx.x * 4 + (threadIdx.x >> 6);  // 0..1023
  int lane = threadIdx.x & 63;
  int rt0 = (gw >> 4) * 2;  // row tiles rt0, rt0+1
  int ct0 = (gw & 15) * 2;  // col tiles ct0, ct0+1

  floatx4 acc00 = {0,0,0,0}, acc01 = {0,0,0,0}, acc10 = {0,0,0,0}, acc11 = {0,0,0,0};
#pragma unroll 4
  for (int ki = 0; ki < NKI; ++ki) {
    bf16x8 a0 = *(const bf16x8*)(Ap + ((long)((rt0 + 0) * NKI + ki) * 64 + lane) * 8);
    bf16x8 a1 = *(const bf16x8*)(Ap + ((long)((rt0 + 1) * NKI + ki) * 64 + lane) * 8);
    bf16x8 b0 = *(const bf16x8*)(Bp + ((long)((ct0 + 0) * NKI + ki) * 64 + lane) * 8);
    bf16x8 b1v = *(const bf16x8*)(Bp + ((long)((ct0 + 1) * NKI + ki) * 64 + lane) * 8);
    acc00 = __builtin_amdgcn_mfma_f32_16x16x32_bf16(a0, b0, acc00, 0, 0, 0);
    acc01 = __builtin_amdgcn_mfma_f32_16x16x32_bf16(a0, b1v, acc01, 0, 0, 0);
    acc10 = __builtin_amdgcn_mfma_f32_16x16x32_bf16(a1, b0, acc10, 0, 0, 0);
    acc11 = __builtin_amdgcn_mfma_f32_16x16x32_bf16(a1, b1v, acc11, 0, 0, 0);
  }
  int col = lane & 15, quad = lane >> 4;
  floatx4 accs[2][2] = {{acc00, acc01}, {acc10, acc11}};
#pragma unroll
  for (int i = 0; i < 2; ++i) {
#pragma unroll
    for (int c = 0; c < 2; ++c) {
      int n = (ct0 + c) * 16 + col;
      float bb = b2[n];
#pragma unroll
      for (int r = 0; r < 4; ++r) {
        int row = (rt0 + i) * 16 + quad * 4 + r;
        H2[row * NH + n] = fast_tanh(accs[i][c][r] + bb);
      }
    }
  }
}

// ---------------------------------------------------------------------------
// Kernel 3: out[s, i<32] = H2[s,:] @ W3[:,i] + b3[i]; also zeroes div slot.
// ---------------------------------------------------------------------------
__global__ __launch_bounds__(256) void k_dx(
    const float* __restrict__ H2, const float* __restrict__ W3,
    const float* __restrict__ b3, float* __restrict__ out) {
  int g = blockIdx.x * 256 + threadIdx.x;  // 0 .. NB*ND-1
  int s = g >> 5;
  int i = g & (ND - 1);
  if (i == 0) out[s * (ND + 1) + ND] = 0.f;  // zero divergence slot for k_div
  const float* h2 = H2 + s * NH;
  float a0 = b3[i], a1 = 0.f, a2 = 0.f, a3 = 0.f;
#pragma unroll 4
  for (int k = 0; k < NH; k += 4) {
    float4 h = *(const float4*)&h2[k];
    a0 += h.x * W3[(k + 0) * ND + i];
    a1 += h.y * W3[(k + 1) * ND + i];
    a2 += h.z * W3[(k + 2) * ND + i];
    a3 += h.w * W3[(k + 3) * ND + i];
  }
  out[s * (ND + 1) + i] = (a0 + a1) + (a2 + a3);
}

// ---------------------------------------------------------------------------
// Kernel 4: div[s] += sum_k (D1 @ M)[s,k] * (1 - H2[s,k]^2)
// Same MFMA structure as k_h2; epilogue weights by d2, reduces each row
// across the 16 lanes of its quad, then atomicAdd per row (col-split partial).
// ---------------------------------------------------------------------------
__global__ __launch_bounds__(256) void k_div(
    const __bf16* __restrict__ Ap, const __bf16* __restrict__ Bp,
    const float* __restrict__ H2, float* __restrict__ out) {
  int gw = blockIdx.x * 4 + (threadIdx.x >> 6);
  int lane = threadIdx.x & 63;
  int rt0 = (gw >> 4) * 2;
  int ct0 = (gw & 15) * 2;

  floatx4 acc00 = {0,0,0,0}, acc01 = {0,0,0,0}, acc10 = {0,0,0,0}, acc11 = {0,0,0,0};
#pragma unroll 4
  for (int ki = 0; ki < NKI; ++ki) {
    bf16x8 a0 = *(const bf16x8*)(Ap + ((long)((rt0 + 0) * NKI + ki) * 64 + lane) * 8);
    bf16x8 a1 = *(const bf16x8*)(Ap + ((long)((rt0 + 1) * NKI + ki) * 64 + lane) * 8);
    bf16x8 b0 = *(const bf16x8*)(Bp + ((long)((ct0 + 0) * NKI + ki) * 64 + lane) * 8);
    bf16x8 b1v = *(const bf16x8*)(Bp + ((long)((ct0 + 1) * NKI + ki) * 64 + lane) * 8);
    acc00 = __builtin_amdgcn_mfma_f32_16x16x32_bf16(a0, b0, acc00, 0, 0, 0);
    acc01 = __builtin_amdgcn_mfma_f32_16x16x32_bf16(a0, b1v, acc01, 0, 0, 0);
    acc10 = __builtin_amdgcn_mfma_f32_16x16x32_bf16(a1, b0, acc10, 0, 0, 0);
    acc11 = __builtin_amdgcn_mfma_f32_16x16x32_bf16(a1, b1v, acc11, 0, 0, 0);
  }
  int col = lane & 15, quad = lane >> 4;
  floatx4 accs[2][2] = {{acc00, acc01}, {acc10, acc11}};
#pragma unroll
  for (int i = 0; i < 2; ++i) {
#pragma unroll
    for (int r = 0; r < 4; ++r) {
      int row = (rt0 + i) * 16 + quad * 4 + r;
      float v = 0.f;
#pragma unroll
      for (int c = 0; c < 2; ++c) {
        int n = (ct0 + c) * 16 + col;
        float h2 = H2[row * NH + n];
        v += accs[i][c][r] * (1.f - h2 * h2);
      }
      // reduce across the 16 lanes of this quad (cols)
      v += __shfl_xor(v, 1);
      v += __shfl_xor(v, 2);
      v += __shfl_xor(v, 4);
      v += __shfl_xor(v, 8);
      if (col == 0) atomicAdd(&out[row * (ND + 1) + ND], v);
    }
  }
}

// ---------------------------------------------------------------------------
extern "C" void kernel_launch(void* const* d_in, const int* in_sizes, int n_in,
                              void* d_out, int out_size, void* d_ws, size_t ws_size,
                              hipStream_t stream) {
  const float* t  = (const float*)d_in[0];
  const float* x  = (const float*)d_in[1];
  const float* W1 = (const float*)d_in[2];
  const float* b1 = (const float*)d_in[3];
  const float* W2 = (const float*)d_in[4];
  const float* b2 = (const float*)d_in[5];
  const float* W3 = (const float*)d_in[6];
  const float* b3 = (const float*)d_in[7];
  float* out = (float*)d_out;

  __bf16* W2p = (__bf16*)d_ws;            // 512*512
  __bf16* Mp  = W2p + NH * NH;            // 512*512
  __bf16* H1p = Mp + NH * NH;             // 2048*512
  __bf16* D1p = H1p + NB * NH;            // 2048*512
  float*  H2  = (float*)(D1p + NB * NH);  // 2048*512 fp32

  k_prep<<<256, 256, 0, stream>>>(W1, W2, W3, W2p, Mp);
  k_h1<<<512, 256, 0, stream>>>(x, t, W1, b1, H1p, D1p);
  k_h2<<<256, 256, 0, stream>>>(H1p, W2p, b2, H2);
  k_dx<<<256, 256, 0, stream>>>(H2, W3, b3, out);
  k_div<<<256, 256, 0, stream>>>(D1p, Mp, H2, out);
}

// Round 3
// 109.406 us; speedup vs baseline: 1.9438x; 1.1149x over previous
//
#include <hip/hip_runtime.h>
#include <math.h>

// Problem sizes
constexpr int NB = 2048;  // batch
constexpr int ND = 32;    // data dim (x has ND+1 cols, last is t)
constexpr int NH = 512;   // hidden
constexpr int NKI = NH / 32;  // K-iterations of 32 per MFMA chain = 16

typedef __bf16 bf16x8 __attribute__((ext_vector_type(8)));
typedef float floatx4 __attribute__((ext_vector_type(4)));

__device__ inline float fast_tanh(float x) {
  float e = __expf(2.f * x);
  return 1.f - 2.f / (e + 1.f);
}

// Fragment pack index: elem = ((tile*NKI + ki)*64 + lane)*8 + j
// A-frag (16x16x32): row m = tile*16 + (lane&15), k = ki*32 + (lane>>4)*8 + j
// B-frag:            col n = tile*16 + (lane&15), k = ki*32 + (lane>>4)*8 + j
// C/D frag:          col = lane&15, row = (lane>>4)*4 + reg   [m89-verified]

// ---------------------------------------------------------------------------
// Kernel 0 (fused prep): blocks [0,512): H1/D1 bf16 A-frag packs + zero d_out.
// Blocks [512,768): W2p/Mp bf16 B-frag packs + W3T (32x512 fp32 transpose).
//   M[j,k] = W2[j,k] * G[k,j], G[k,j] = sum_{i<32} W3[k,i]*W1[i,j].
// ---------------------------------------------------------------------------
__global__ __launch_bounds__(256) void k_pre(
    const float* __restrict__ x, const float* __restrict__ t,
    const float* __restrict__ W1, const float* __restrict__ b1,
    const float* __restrict__ W2, const float* __restrict__ W3,
    __bf16* __restrict__ H1p, __bf16* __restrict__ D1p,
    __bf16* __restrict__ W2p, __bf16* __restrict__ Mp,
    float* __restrict__ W3T, float* __restrict__ out) {
  if (blockIdx.x < 512) {
    // ---- H1 / D1 producer ----
    int gid = blockIdx.x * 256 + threadIdx.x;  // 0..131071
    if (gid < NB * (ND + 1)) out[gid] = 0.f;   // zero output for atomics
    int lane = gid & 63;
    int ki = (gid >> 6) & (NKI - 1);
    int rt = gid >> 10;                  // 0..127
    int m = rt * 16 + (lane & 15);       // sample row
    int k0 = ki * 32 + (lane >> 4) * 8;  // 8 contiguous k
    const float* xs = x + m * (ND + 1);

    float acc[8];
#pragma unroll
    for (int j = 0; j < 8; ++j) acc[j] = b1[k0 + j];
#pragma unroll
    for (int i = 0; i < ND; ++i) {
      float xv = xs[i];
      float4 u = *(const float4*)&W1[i * NH + k0];
      float4 v = *(const float4*)&W1[i * NH + k0 + 4];
      acc[0] += xv * u.x; acc[1] += xv * u.y;
      acc[2] += xv * u.z; acc[3] += xv * u.w;
      acc[4] += xv * v.x; acc[5] += xv * v.y;
      acc[6] += xv * v.z; acc[7] += xv * v.w;
    }
    {
      float tv = t[0];
      float4 u = *(const float4*)&W1[ND * NH + k0];
      float4 v = *(const float4*)&W1[ND * NH + k0 + 4];
      acc[0] += tv * u.x; acc[1] += tv * u.y;
      acc[2] += tv * u.z; acc[3] += tv * u.w;
      acc[4] += tv * v.x; acc[5] += tv * v.y;
      acc[6] += tv * v.z; acc[7] += tv * v.w;
    }
    __bf16 hv[8], dv[8];
#pragma unroll
    for (int j = 0; j < 8; ++j) {
      float h = fast_tanh(acc[j]);
      hv[j] = (__bf16)h;
      dv[j] = (__bf16)(1.f - h * h);
    }
    long off = (long)gid * 8;
    *(bf16x8*)(H1p + off) = *(bf16x8*)hv;
    *(bf16x8*)(D1p + off) = *(bf16x8*)dv;
  } else {
    // ---- weight packers ----
    int pb = blockIdx.x - 512;                 // 0..255
    int gid2 = pb * 256 + threadIdx.x;         // 0..65535
    if (gid2 < ND * NH)                        // W3T[i][k] = W3[k][i]
      W3T[gid2] = W3[(gid2 & (NH - 1)) * ND + (gid2 >> 9)];

    bool doM = pb >= 128;
    int gid = (pb & 127) * 256 + threadIdx.x;  // 0..32767
    int lane = gid & 63;
    int ki = (gid >> 6) & (NKI - 1);
    int ct = gid >> 10;                  // 0..31
    int n = ct * 16 + (lane & 15);       // output column
    int k0 = ki * 32 + (lane >> 4) * 8;  // k-range start (8 contiguous)
    long off = (long)gid * 8;

    if (!doM) {
      __bf16 v[8];
#pragma unroll
      for (int j = 0; j < 8; ++j) v[j] = (__bf16)W2[(k0 + j) * NH + n];
      *(bf16x8*)(W2p + off) = *(bf16x8*)v;
    } else {
      float acc[8];
#pragma unroll
      for (int j = 0; j < 8; ++j) acc[j] = 0.f;
      for (int i = 0; i < ND; ++i) {
        float w3 = W3[n * ND + i];
        float4 u = *(const float4*)&W1[i * NH + k0];
        float4 v = *(const float4*)&W1[i * NH + k0 + 4];
        acc[0] += w3 * u.x; acc[1] += w3 * u.y;
        acc[2] += w3 * u.z; acc[3] += w3 * u.w;
        acc[4] += w3 * v.x; acc[5] += w3 * v.y;
        acc[6] += w3 * v.z; acc[7] += w3 * v.w;
      }
      __bf16 v[8];
#pragma unroll
      for (int j = 0; j < 8; ++j)
        v[j] = (__bf16)(W2[(k0 + j) * NH + n] * acc[j]);
      *(bf16x8*)(Mp + off) = *(bf16x8*)v;
    }
  }
}

// ---------------------------------------------------------------------------
// Kernel 1 (fused main): block = 16 rows x 256 cols (K-split 2-way over cols
// of the hidden layer). Dual MFMA GEMMs (H1@W2 and D1@M) share A-side frags.
// Epilogue: h2=tanh in-register -> LDS tile; div = sum d2*(D1@M) via shuffle
// + LDS + atomicAdd; dx = h2 @ W3 from LDS tile with broadcast W3T loads,
// atomicAdd partials (out pre-zeroed by k_pre).
// ---------------------------------------------------------------------------
__global__ __launch_bounds__(256) void k_main(
    const __bf16* __restrict__ Ah, const __bf16* __restrict__ Ad,
    const __bf16* __restrict__ W2p, const __bf16* __restrict__ Mp,
    const float* __restrict__ b2, const float* __restrict__ W3T,
    const float* __restrict__ b3, float* __restrict__ out) {
  __shared__ float h2s[16][260];   // +4 pad: stride 260 -> 2-way banks (free)
  __shared__ float divred[4][16];

  int bid = blockIdx.x;            // 0..255
  int rt = bid >> 1;               // row tile 0..127
  int half = bid & 1;              // which 256-col half
  int tid = threadIdx.x;
  int w = tid >> 6, lane = tid & 63;
  int col = lane & 15, quad = lane >> 4;
  int ct0 = half * 16 + w * 4;     // this wave's 4 global col-tiles

  floatx4 accH[4] = {{0,0,0,0},{0,0,0,0},{0,0,0,0},{0,0,0,0}};
  floatx4 accM[4] = {{0,0,0,0},{0,0,0,0},{0,0,0,0},{0,0,0,0}};
  long abase = (long)rt * NKI;
#pragma unroll 2
  for (int ki = 0; ki < NKI; ++ki) {
    bf16x8 ah = *(const bf16x8*)(Ah + ((abase + ki) * 64 + lane) * 8);
    bf16x8 ad = *(const bf16x8*)(Ad + ((abase + ki) * 64 + lane) * 8);
#pragma unroll
    for (int c = 0; c < 4; ++c) {
      long boff = ((long)((ct0 + c) * NKI + ki) * 64 + lane) * 8;
      bf16x8 bw = *(const bf16x8*)(W2p + boff);
      bf16x8 bm = *(const bf16x8*)(Mp + boff);
      accH[c] = __builtin_amdgcn_mfma_f32_16x16x32_bf16(ah, bw, accH[c], 0, 0, 0);
      accM[c] = __builtin_amdgcn_mfma_f32_16x16x32_bf16(ad, bm, accM[c], 0, 0, 0);
    }
  }

  // Epilogue: h2 -> LDS; div partial per row
  float divv[4] = {0.f, 0.f, 0.f, 0.f};
#pragma unroll
  for (int c = 0; c < 4; ++c) {
    int n = (ct0 + c) * 16 + col;       // global hidden col
    int nc = (w * 4 + c) * 16 + col;    // local col within block's 256
    float bb = b2[n];
#pragma unroll
    for (int r = 0; r < 4; ++r) {
      float h2 = fast_tanh(accH[c][r] + bb);
      h2s[quad * 4 + r][nc] = h2;
      divv[r] += accM[c][r] * (1.f - h2 * h2);
    }
  }
#pragma unroll
  for (int r = 0; r < 4; ++r) {
    float v = divv[r];
    v += __shfl_xor(v, 1);
    v += __shfl_xor(v, 2);
    v += __shfl_xor(v, 4);
    v += __shfl_xor(v, 8);
    if (col == 0) divred[w][quad * 4 + r] = v;
  }
  __syncthreads();
  if (tid < 16) {
    float v = divred[0][tid] + divred[1][tid] + divred[2][tid] + divred[3][tid];
    atomicAdd(&out[(rt * 16 + tid) * (ND + 1) + ND], v);
  }

  // dx phase: out[row, i] += sum_{k in this half} h2[row,k] * W3[k,i]
  int row = tid & 15;        // local row
  int i0 = tid >> 4;         // 0..15 -> output cols {2*i0, 2*i0+1}
  const float* w3a = W3T + (long)(i0 * 2 + 0) * NH + half * 256;
  const float* w3b = W3T + (long)(i0 * 2 + 1) * NH + half * 256;
  float a0 = 0.f, a1 = 0.f;
#pragma unroll 4
  for (int kk = 0; kk < 256; kk += 4) {
    float4 h = *(const float4*)&h2s[row][kk];
    float4 wa = *(const float4*)&w3a[kk];
    float4 wb = *(const float4*)&w3b[kk];
    a0 += h.x * wa.x + h.y * wa.y + h.z * wa.z + h.w * wa.w;
    a1 += h.x * wb.x + h.y * wb.y + h.z * wb.z + h.w * wb.w;
  }
  if (half == 0) { a0 += b3[i0 * 2]; a1 += b3[i0 * 2 + 1]; }
  float* orow = out + (long)(rt * 16 + row) * (ND + 1);
  atomicAdd(&orow[i0 * 2], a0);
  atomicAdd(&orow[i0 * 2 + 1], a1);
}

// ---------------------------------------------------------------------------
extern "C" void kernel_launch(void* const* d_in, const int* in_sizes, int n_in,
                              void* d_out, int out_size, void* d_ws, size_t ws_size,
                              hipStream_t stream) {
  const float* t  = (const float*)d_in[0];
  const float* x  = (const float*)d_in[1];
  const float* W1 = (const float*)d_in[2];
  const float* b1 = (const float*)d_in[3];
  const float* W2 = (const float*)d_in[4];
  const float* b2 = (const float*)d_in[5];
  const float* W3 = (const float*)d_in[6];
  const float* b3 = (const float*)d_in[7];
  float* out = (float*)d_out;

  __bf16* W2p = (__bf16*)d_ws;            // 512*512
  __bf16* Mp  = W2p + NH * NH;            // 512*512
  __bf16* H1p = Mp + NH * NH;             // 2048*512
  __bf16* D1p = H1p + NB * NH;            // 2048*512
  float*  W3T = (float*)(D1p + NB * NH);  // 32*512 fp32

  k_pre<<<768, 256, 0, stream>>>(x, t, W1, b1, W2, W3, H1p, D1p, W2p, Mp, W3T, out);
  k_main<<<256, 256, 0, stream>>>(H1p, D1p, W2p, Mp, b2, W3T, b3, out);
}

// Round 4
// 104.716 us; speedup vs baseline: 2.0309x; 1.0448x over previous
//
#include <hip/hip_runtime.h>
#include <math.h>

// Problem sizes
constexpr int NB = 2048;  // batch
constexpr int ND = 32;    // data dim (x has ND+1 cols, last is t)
constexpr int NH = 512;   // hidden
constexpr int NKI = NH / 32;  // K-iterations of 32 per MFMA chain = 16

typedef __bf16 bf16x8 __attribute__((ext_vector_type(8)));
typedef __bf16 bf16x4 __attribute__((ext_vector_type(4)));
typedef float floatx4 __attribute__((ext_vector_type(4)));

__device__ inline float fast_tanh(float x) {
  float e = __expf(2.f * x);
  return 1.f - 2.f / (e + 1.f);
}

// Fragment pack index: elem = ((tile*NKI + ki)*64 + lane)*8 + j
// A-frag (16x16x32): row m = tile*16 + (lane&15), k = ki*32 + (lane>>4)*8 + j
// B-frag:            col n = tile*16 + (lane&15), k = ki*32 + (lane>>4)*8 + j
// C/D frag:          col = lane&15, row = (lane>>4)*4 + reg   [m89-verified]

// ---------------------------------------------------------------------------
// Kernel 0: weight prep. Blocks [0,128): W2p B-frag pack. [128,256): Mp pack,
//   M[j,n] = W2[j,n] * G[n,j], G[n,j] = sum_{i<32} W3[n,i]*W1[i,j].
// Also: W3T (32x512 fp32 transpose of W3) and zeroing d_out for atomics.
// ---------------------------------------------------------------------------
__global__ __launch_bounds__(256) void k_pre(
    const float* __restrict__ W1, const float* __restrict__ W2,
    const float* __restrict__ W3, __bf16* __restrict__ W2p,
    __bf16* __restrict__ Mp, float* __restrict__ W3T,
    float* __restrict__ out) {
  int g = blockIdx.x * 256 + threadIdx.x;  // 0..65535
  for (int idx = g; idx < NB * (ND + 1); idx += 65536) out[idx] = 0.f;
  if (g < ND * NH)  // W3T[i][k] = W3[k][i]
    W3T[g] = W3[(g & (NH - 1)) * ND + (g >> 9)];

  bool doM = blockIdx.x >= 128;
  int gid = (blockIdx.x & 127) * 256 + threadIdx.x;  // 0..32767
  int lane = gid & 63;
  int ki = (gid >> 6) & (NKI - 1);
  int ct = gid >> 10;                  // 0..31
  int n = ct * 16 + (lane & 15);       // output column (hidden-2 index)
  int k0 = ki * 32 + (lane >> 4) * 8;  // k-range start (8 contiguous, hidden-1)
  long off = (long)gid * 8;

  if (!doM) {
    __bf16 v[8];
#pragma unroll
    for (int j = 0; j < 8; ++j) v[j] = (__bf16)W2[(k0 + j) * NH + n];
    *(bf16x8*)(W2p + off) = *(bf16x8*)v;
  } else {
    float acc[8];
#pragma unroll
    for (int j = 0; j < 8; ++j) acc[j] = 0.f;
    for (int i = 0; i < ND; ++i) {
      float w3 = W3[n * ND + i];
      float4 u = *(const float4*)&W1[i * NH + k0];
      float4 v = *(const float4*)&W1[i * NH + k0 + 4];
      acc[0] += w3 * u.x; acc[1] += w3 * u.y;
      acc[2] += w3 * u.z; acc[3] += w3 * u.w;
      acc[4] += w3 * v.x; acc[5] += w3 * v.y;
      acc[6] += w3 * v.z; acc[7] += w3 * v.w;
    }
    __bf16 v[8];
#pragma unroll
    for (int j = 0; j < 8; ++j)
      v[j] = (__bf16)(W2[(k0 + j) * NH + n] * acc[j]);
    *(bf16x8*)(Mp + off) = *(bf16x8*)v;
  }
}

// ---------------------------------------------------------------------------
// Kernel 1 (fully fused main): block = (row-tile rt, col half). Phases:
//  (1) stage x-tile; compute H1/D1 in fp32 straight into LDS A-frag layout
//  (2) dual MFMA GEMM: accH = H1@W2, accM = D1@M (A from LDS, B from packs)
//  (3) h2 = tanh(accH+b2) -> LDS; div = sum d2*accM (shuffle+LDS+atomicAdd)
//  (4) dx = h2 @ W3 from LDS tile, atomicAdd partials (out pre-zeroed)
// ---------------------------------------------------------------------------
__global__ __launch_bounds__(256) void k_main(
    const float* __restrict__ x, const float* __restrict__ t,
    const float* __restrict__ W1, const float* __restrict__ b1,
    const __bf16* __restrict__ W2p, const __bf16* __restrict__ Mp,
    const float* __restrict__ b2, const float* __restrict__ W3T,
    const float* __restrict__ b3, float* __restrict__ out) {
  __shared__ __bf16 aH[16 * NH];   // A-frag layout, 16 KB
  __shared__ __bf16 aD[16 * NH];   // 16 KB
  __shared__ float xs[16][36];     // x tile (33 used, pad to 36)
  __shared__ float h2s[16][260];   // h2 tile, +4 pad
  __shared__ float divred[4][16];

  int bid = blockIdx.x;  // 0..255
  int rt = bid >> 1;     // row tile 0..127
  int half = bid & 1;    // which 256-col half of hidden-2
  int tid = threadIdx.x;

  // ---- phase 0: stage x tile ----
  for (int idx = tid; idx < 16 * 33; idx += 256) {
    int r = idx / 33, i = idx - r * 33;
    xs[r][i] = x[(rt * 16 + r) * (ND + 1) + i];
  }
  float tv = t[0];
  __syncthreads();

  // ---- phase 1: H1/D1 -> LDS A-frags ----
  {
    int r = tid >> 4;              // 0..15 local row
    int cb = (tid & 15) * 4;       // col base within 64-chunk
#pragma unroll
    for (int it = 0; it < 8; ++it) {
      int c0 = cb + it * 64;       // 4 contiguous cols
      float4 bb = *(const float4*)&b1[c0];
      float a0 = bb.x, a1 = bb.y, a2 = bb.z, a3 = bb.w;
#pragma unroll
      for (int i = 0; i < ND; ++i) {
        float xv = xs[r][i];
        float4 w = *(const float4*)&W1[i * NH + c0];
        a0 += xv * w.x; a1 += xv * w.y; a2 += xv * w.z; a3 += xv * w.w;
      }
      {
        float4 w = *(const float4*)&W1[ND * NH + c0];
        a0 += tv * w.x; a1 += tv * w.y; a2 += tv * w.z; a3 += tv * w.w;
      }
      float h0 = fast_tanh(a0), h1 = fast_tanh(a1);
      float h2 = fast_tanh(a2), h3 = fast_tanh(a3);
      __bf16 hv[4] = {(__bf16)h0, (__bf16)h1, (__bf16)h2, (__bf16)h3};
      __bf16 dv[4] = {(__bf16)(1.f - h0 * h0), (__bf16)(1.f - h1 * h1),
                      (__bf16)(1.f - h2 * h2), (__bf16)(1.f - h3 * h3)};
      // A-frag address for (r, c0): ki=c0>>5, lane=r|(((c0>>3)&3)<<4), j=c0&7
      int ki = c0 >> 5;
      int lane = r | (((c0 >> 3) & 3) << 4);
      int j = c0 & 7;
      int ofs = (ki * 64 + lane) * 8 + j;
      *(bf16x4*)(aH + ofs) = *(bf16x4*)hv;
      *(bf16x4*)(aD + ofs) = *(bf16x4*)dv;
    }
  }
  __syncthreads();

  // ---- phase 2: dual MFMA GEMM ----
  int w = tid >> 6, lane = tid & 63;
  int col = lane & 15, quad = lane >> 4;
  int ct0 = half * 16 + w * 4;  // this wave's 4 global col-tiles

  floatx4 accH[4] = {{0,0,0,0},{0,0,0,0},{0,0,0,0},{0,0,0,0}};
  floatx4 accM[4] = {{0,0,0,0},{0,0,0,0},{0,0,0,0},{0,0,0,0}};
#pragma unroll 2
  for (int ki = 0; ki < NKI; ++ki) {
    bf16x8 ah = *(const bf16x8*)(aH + (ki * 64 + lane) * 8);
    bf16x8 ad = *(const bf16x8*)(aD + (ki * 64 + lane) * 8);
#pragma unroll
    for (int c = 0; c < 4; ++c) {
      long boff = ((long)((ct0 + c) * NKI + ki) * 64 + lane) * 8;
      bf16x8 bw = *(const bf16x8*)(W2p + boff);
      bf16x8 bm = *(const bf16x8*)(Mp + boff);
      accH[c] = __builtin_amdgcn_mfma_f32_16x16x32_bf16(ah, bw, accH[c], 0, 0, 0);
      accM[c] = __builtin_amdgcn_mfma_f32_16x16x32_bf16(ad, bm, accM[c], 0, 0, 0);
    }
  }

  // ---- phase 3: h2 -> LDS, divergence partials ----
  float divv[4] = {0.f, 0.f, 0.f, 0.f};
#pragma unroll
  for (int c = 0; c < 4; ++c) {
    int n = (ct0 + c) * 16 + col;     // global hidden-2 col
    int nc = (w * 4 + c) * 16 + col;  // local col within 256
    float bb = b2[n];
#pragma unroll
    for (int r = 0; r < 4; ++r) {
      float h2 = fast_tanh(accH[c][r] + bb);
      h2s[quad * 4 + r][nc] = h2;
      divv[r] += accM[c][r] * (1.f - h2 * h2);
    }
  }
#pragma unroll
  for (int r = 0; r < 4; ++r) {
    float v = divv[r];
    v += __shfl_xor(v, 1);
    v += __shfl_xor(v, 2);
    v += __shfl_xor(v, 4);
    v += __shfl_xor(v, 8);
    if (col == 0) divred[w][quad * 4 + r] = v;
  }
  __syncthreads();
  if (tid < 16) {
    float v = divred[0][tid] + divred[1][tid] + divred[2][tid] + divred[3][tid];
    atomicAdd(&out[(rt * 16 + tid) * (ND + 1) + ND], v);
  }

  // ---- phase 4: dx = h2 @ W3 (this half's 256 k) ----
  int row = tid & 15;  // local row
  int i0 = tid >> 4;   // 0..15 -> output cols {2*i0, 2*i0+1}
  const float* w3a = W3T + (long)(i0 * 2 + 0) * NH + half * 256;
  const float* w3b = W3T + (long)(i0 * 2 + 1) * NH + half * 256;
  float a0 = 0.f, a1 = 0.f;
#pragma unroll 4
  for (int kk = 0; kk < 256; kk += 4) {
    float4 h = *(const float4*)&h2s[row][kk];
    float4 wa = *(const float4*)&w3a[kk];
    float4 wb = *(const float4*)&w3b[kk];
    a0 += h.x * wa.x + h.y * wa.y + h.z * wa.z + h.w * wa.w;
    a1 += h.x * wb.x + h.y * wb.y + h.z * wb.z + h.w * wb.w;
  }
  if (half == 0) { a0 += b3[i0 * 2]; a1 += b3[i0 * 2 + 1]; }
  float* orow = out + (long)(rt * 16 + row) * (ND + 1);
  atomicAdd(&orow[i0 * 2], a0);
  atomicAdd(&orow[i0 * 2 + 1], a1);
}

// ---------------------------------------------------------------------------
extern "C" void kernel_launch(void* const* d_in, const int* in_sizes, int n_in,
                              void* d_out, int out_size, void* d_ws, size_t ws_size,
                              hipStream_t stream) {
  const float* t  = (const float*)d_in[0];
  const float* x  = (const float*)d_in[1];
  const float* W1 = (const float*)d_in[2];
  const float* b1 = (const float*)d_in[3];
  const float* W2 = (const float*)d_in[4];
  const float* b2 = (const float*)d_in[5];
  const float* W3 = (const float*)d_in[6];
  const float* b3 = (const float*)d_in[7];
  float* out = (float*)d_out;

  __bf16* W2p = (__bf16*)d_ws;            // 512*512 bf16
  __bf16* Mp  = W2p + NH * NH;            // 512*512 bf16
  float*  W3T = (float*)(Mp + NH * NH);   // 32*512 fp32

  k_pre<<<256, 256, 0, stream>>>(W1, W2, W3, W2p, Mp, W3T, out);
  k_main<<<256, 256, 0, stream>>>(x, t, W1, b1, W2p, Mp, b2, W3T, b3, out);
}

// Round 5
// 103.045 us; speedup vs baseline: 2.0638x; 1.0162x over previous
//
#include <hip/hip_runtime.h>
#include <math.h>

// Problem sizes
constexpr int NB = 2048;  // batch
constexpr int ND = 32;    // data dim (x has ND+1 cols; col ND is replaced by t)
constexpr int NH = 512;   // hidden
constexpr int NKI = NH / 32;  // K-iterations of 32 per MFMA chain = 16

typedef __bf16 bf16x8 __attribute__((ext_vector_type(8)));
typedef float floatx4 __attribute__((ext_vector_type(4)));

__device__ inline float fast_tanh(float x) {
  float e = __expf(2.f * x);
  return 1.f - 2.f / (e + 1.f);
}

// Fragment pack index: elem = ((tile*nki + ki)*64 + lane)*8 + j
// A-frag (16x16x32): row m = tile*16 + (lane&15), k = ki*32 + (lane>>4)*8 + j
// B-frag:            col n = tile*16 + (lane&15), k = ki*32 + (lane>>4)*8 + j
// C/D frag:          col = lane&15, row = (lane>>4)*4 + reg   [m89-verified]

// ---------------------------------------------------------------------------
// Kernel 0: weight prep.
//  - Blocks [0,128): W2p B-frag pack; blocks [128,256): Mp B-frag pack,
//      M[j,n] = W2[j,n] * G[n,j], G[n,j] = sum_{i<32} W3[n,i]*W1[i,j].
//  - W3T (32x512 fp32 transpose of W3), W1p (B-frag of W1 with K padded to
//    64: rows 0..32 real, 33..63 zero), and zeroing d_out for atomics.
// ---------------------------------------------------------------------------
__global__ __launch_bounds__(256) void k_pre(
    const float* __restrict__ W1, const float* __restrict__ W2,
    const float* __restrict__ W3, __bf16* __restrict__ W2p,
    __bf16* __restrict__ Mp, float* __restrict__ W3T,
    __bf16* __restrict__ W1p, float* __restrict__ out) {
  int g = blockIdx.x * 256 + threadIdx.x;  // 0..65535
  for (int idx = g; idx < NB * (ND + 1); idx += 65536) out[idx] = 0.f;
  if (g < ND * NH)  // W3T[i][k] = W3[k][i]
    W3T[g] = W3[(g & (NH - 1)) * ND + (g >> 9)];
  if (g < 4096) {   // W1p: ct(32) x ki(2) x lane(64), 8 bf16 each
    int lane1 = g & 63;
    int ki1 = (g >> 6) & 1;
    int ct1 = g >> 7;
    int n1 = ct1 * 16 + (lane1 & 15);
    int k0 = ki1 * 32 + (lane1 >> 4) * 8;
    __bf16 v[8];
#pragma unroll
    for (int j = 0; j < 8; ++j) {
      int k = k0 + j;
      v[j] = (k <= ND) ? (__bf16)W1[k * NH + n1] : (__bf16)0.f;
    }
    *(bf16x8*)(W1p + (long)g * 8) = *(bf16x8*)v;
  }

  bool doM = blockIdx.x >= 128;
  int gid = (blockIdx.x & 127) * 256 + threadIdx.x;  // 0..32767
  int lane = gid & 63;
  int ki = (gid >> 6) & (NKI - 1);
  int ct = gid >> 10;                  // 0..31
  int n = ct * 16 + (lane & 15);       // output column (hidden-2 index)
  int k0 = ki * 32 + (lane >> 4) * 8;  // k-range start (8 contiguous, hidden-1)
  long off = (long)gid * 8;

  if (!doM) {
    __bf16 v[8];
#pragma unroll
    for (int j = 0; j < 8; ++j) v[j] = (__bf16)W2[(k0 + j) * NH + n];
    *(bf16x8*)(W2p + off) = *(bf16x8*)v;
  } else {
    float acc[8];
#pragma unroll
    for (int j = 0; j < 8; ++j) acc[j] = 0.f;
    for (int i = 0; i < ND; ++i) {
      float w3 = W3[n * ND + i];
      float4 u = *(const float4*)&W1[i * NH + k0];
      float4 v = *(const float4*)&W1[i * NH + k0 + 4];
      acc[0] += w3 * u.x; acc[1] += w3 * u.y;
      acc[2] += w3 * u.z; acc[3] += w3 * u.w;
      acc[4] += w3 * v.x; acc[5] += w3 * v.y;
      acc[6] += w3 * v.z; acc[7] += w3 * v.w;
    }
    __bf16 v[8];
#pragma unroll
    for (int j = 0; j < 8; ++j)
      v[j] = (__bf16)(W2[(k0 + j) * NH + n] * acc[j]);
    *(bf16x8*)(Mp + off) = *(bf16x8*)v;
  }
}

// ---------------------------------------------------------------------------
// Kernel 1 (fused main): block = (32-row group rb, col quarter q). Phases:
//  (0) build bf16 x A-frag in LDS (2 row-tiles x K=64 padded)
//  (1) H1 = x@W1 via MFMA; tanh/1-h^2 -> LDS A-frag packs (all 512 h1 cols)
//  (2) dual MFMA GEMM over this block's 128 h2 cols: accH=H1@W2, accM=D1@M
//  (3) h2=tanh(accH+b2) -> LDS; div partials (shuffle+LDS+atomicAdd)
//  (4) dx = h2 @ W3 (this quarter's 128 k), atomicAdd (out pre-zeroed)
// ---------------------------------------------------------------------------
__global__ __launch_bounds__(256) void k_main(
    const float* __restrict__ x, const float* __restrict__ t,
    const __bf16* __restrict__ W1p, const float* __restrict__ b1,
    const __bf16* __restrict__ W2p, const __bf16* __restrict__ Mp,
    const float* __restrict__ b2, const float* __restrict__ W3T,
    const float* __restrict__ b3, float* __restrict__ out) {
  __shared__ __bf16 xf[2 * 2 * 64 * 8];  // x A-frag, 4 KB
  __shared__ __bf16 aH[2 * 16 * 64 * 8]; // H1 A-frag, 32 KB
  __shared__ __bf16 aD[2 * 16 * 64 * 8]; // D1 A-frag, 32 KB
  __shared__ float h2s[32][132];         // h2 tile, +4 pad
  __shared__ float divred[4][32];

  int bid = blockIdx.x;  // 0..255
  int rb = bid >> 2;     // 32-row group 0..63
  int q = bid & 3;       // col quarter of hidden-2
  int tid = threadIdx.x;
  int w = tid >> 6, lane = tid & 63;
  int col = lane & 15, quad = lane >> 4;
  float tv = t[0];

  // ---- phase 0: build x A-frag (one thread per (rt,ki,lane)) ----
  {
    int lane0 = tid & 63;
    int ki0 = (tid >> 6) & 1;
    int rt0 = tid >> 7;
    int row = rb * 32 + rt0 * 16 + (lane0 & 15);
    int k0 = ki0 * 32 + (lane0 >> 4) * 8;
    __bf16 v[8];
#pragma unroll
    for (int j = 0; j < 8; ++j) {
      int k = k0 + j;
      float val = (k < ND) ? x[(long)row * (ND + 1) + k] : (k == ND ? tv : 0.f);
      v[j] = (__bf16)val;
    }
    *(bf16x8*)(xf + (long)tid * 8) = *(bf16x8*)v;
  }
  __syncthreads();

  // ---- phase 1: H1/D1 via MFMA -> LDS A-frags ----
  {
    bf16x8 xa[2][2];
#pragma unroll
    for (int rt = 0; rt < 2; ++rt)
#pragma unroll
      for (int ki = 0; ki < 2; ++ki)
        xa[rt][ki] = *(const bf16x8*)(xf + ((rt * 2 + ki) * 64 + lane) * 8);
#pragma unroll 2
    for (int c8 = 0; c8 < 8; ++c8) {
      int ct1 = w * 8 + c8;  // h1 col-tile 0..31
      floatx4 ac0 = {0, 0, 0, 0}, ac1 = {0, 0, 0, 0};
#pragma unroll
      for (int ki = 0; ki < 2; ++ki) {
        bf16x8 bw = *(const bf16x8*)(W1p + ((long)(ct1 * 2 + ki) * 64 + lane) * 8);
        ac0 = __builtin_amdgcn_mfma_f32_16x16x32_bf16(xa[0][ki], bw, ac0, 0, 0, 0);
        ac1 = __builtin_amdgcn_mfma_f32_16x16x32_bf16(xa[1][ki], bw, ac1, 0, 0, 0);
      }
      int n = ct1 * 16 + col;
      float bb = b1[n];
      int kio = n >> 5, hi = (n >> 3) & 3, j = n & 7;
#pragma unroll
      for (int rt = 0; rt < 2; ++rt) {
        floatx4 a = rt ? ac1 : ac0;
#pragma unroll
        for (int r = 0; r < 4; ++r) {
          float h = fast_tanh(a[r] + bb);
          int lanep = (quad * 4 + r) | (hi << 4);
          int ofs = ((rt * 16 + kio) * 64 + lanep) * 8 + j;
          aH[ofs] = (__bf16)h;
          aD[ofs] = (__bf16)(1.f - h * h);
        }
      }
    }
  }
  __syncthreads();

  // ---- phase 2: dual MFMA GEMM (2 row-tiles x 2 col-tiles per wave) ----
  int ct0 = q * 8 + w * 2;  // this wave's first global h2 col-tile
  floatx4 accH[2][2] = {{{0,0,0,0},{0,0,0,0}},{{0,0,0,0},{0,0,0,0}}};
  floatx4 accM[2][2] = {{{0,0,0,0},{0,0,0,0}},{{0,0,0,0},{0,0,0,0}}};
#pragma unroll 2
  for (int ki = 0; ki < NKI; ++ki) {
    bf16x8 ah0 = *(const bf16x8*)(aH + ((0 * 16 + ki) * 64 + lane) * 8);
    bf16x8 ah1 = *(const bf16x8*)(aH + ((1 * 16 + ki) * 64 + lane) * 8);
    bf16x8 ad0 = *(const bf16x8*)(aD + ((0 * 16 + ki) * 64 + lane) * 8);
    bf16x8 ad1 = *(const bf16x8*)(aD + ((1 * 16 + ki) * 64 + lane) * 8);
#pragma unroll
    for (int cc = 0; cc < 2; ++cc) {
      long boff = ((long)((ct0 + cc) * NKI + ki) * 64 + lane) * 8;
      bf16x8 bw = *(const bf16x8*)(W2p + boff);
      bf16x8 bm = *(const bf16x8*)(Mp + boff);
      accH[0][cc] = __builtin_amdgcn_mfma_f32_16x16x32_bf16(ah0, bw, accH[0][cc], 0, 0, 0);
      accH[1][cc] = __builtin_amdgcn_mfma_f32_16x16x32_bf16(ah1, bw, accH[1][cc], 0, 0, 0);
      accM[0][cc] = __builtin_amdgcn_mfma_f32_16x16x32_bf16(ad0, bm, accM[0][cc], 0, 0, 0);
      accM[1][cc] = __builtin_amdgcn_mfma_f32_16x16x32_bf16(ad1, bm, accM[1][cc], 0, 0, 0);
    }
  }

  // ---- phase 3: h2 -> LDS, divergence partials ----
  float divv[2][4] = {{0, 0, 0, 0}, {0, 0, 0, 0}};
#pragma unroll
  for (int cc = 0; cc < 2; ++cc) {
    int n = (ct0 + cc) * 16 + col;     // global hidden-2 col
    int nc = (w * 2 + cc) * 16 + col;  // local col within 128
    float bb = b2[n];
#pragma unroll
    for (int rt = 0; rt < 2; ++rt) {
#pragma unroll
      for (int r = 0; r < 4; ++r) {
        float h2 = fast_tanh(accH[rt][cc][r] + bb);
        h2s[rt * 16 + quad * 4 + r][nc] = h2;
        divv[rt][r] += accM[rt][cc][r] * (1.f - h2 * h2);
      }
    }
  }
#pragma unroll
  for (int rt = 0; rt < 2; ++rt) {
#pragma unroll
    for (int r = 0; r < 4; ++r) {
      float v = divv[rt][r];
      v += __shfl_xor(v, 1);
      v += __shfl_xor(v, 2);
      v += __shfl_xor(v, 4);
      v += __shfl_xor(v, 8);
      if (col == 0) divred[w][rt * 16 + quad * 4 + r] = v;
    }
  }
  __syncthreads();
  if (tid < 32) {
    float v = divred[0][tid] + divred[1][tid] + divred[2][tid] + divred[3][tid];
    atomicAdd(&out[(long)(rb * 32 + tid) * (ND + 1) + ND], v);
  }

  // ---- phase 4: dx = h2 @ W3 (this quarter's 128 k) ----
  int row = tid & 31;  // local row
  int i0 = tid >> 5;   // 0..7 -> output cols i0*4 .. i0*4+3
  float a4[4] = {0.f, 0.f, 0.f, 0.f};
#pragma unroll 2
  for (int kk = 0; kk < 128; kk += 4) {
    float4 h = *(const float4*)&h2s[row][kk];
#pragma unroll
    for (int ii = 0; ii < 4; ++ii) {
      float4 wv = *(const float4*)&W3T[(long)(i0 * 4 + ii) * NH + q * 128 + kk];
      a4[ii] += h.x * wv.x + h.y * wv.y + h.z * wv.z + h.w * wv.w;
    }
  }
  float* orow = out + (long)(rb * 32 + row) * (ND + 1);
#pragma unroll
  for (int ii = 0; ii < 4; ++ii) {
    float v = a4[ii] + (q == 0 ? b3[i0 * 4 + ii] : 0.f);
    atomicAdd(&orow[i0 * 4 + ii], v);
  }
}

// ---------------------------------------------------------------------------
extern "C" void kernel_launch(void* const* d_in, const int* in_sizes, int n_in,
                              void* d_out, int out_size, void* d_ws, size_t ws_size,
                              hipStream_t stream) {
  const float* t  = (const float*)d_in[0];
  const float* x  = (const float*)d_in[1];
  const float* W1 = (const float*)d_in[2];
  const float* b1 = (const float*)d_in[3];
  const float* W2 = (const float*)d_in[4];
  const float* b2 = (const float*)d_in[5];
  const float* W3 = (const float*)d_in[6];
  const float* b3 = (const float*)d_in[7];
  float* out = (float*)d_out;

  __bf16* W2p = (__bf16*)d_ws;            // 512*512 bf16
  __bf16* Mp  = W2p + NH * NH;            // 512*512 bf16
  float*  W3T = (float*)(Mp + NH * NH);   // 32*512 fp32
  __bf16* W1p = (__bf16*)(W3T + ND * NH); // 32*2*64*8 = 32768 bf16

  k_pre<<<256, 256, 0, stream>>>(W1, W2, W3, W2p, Mp, W3T, W1p, out);
  k_main<<<256, 256, 0, stream>>>(x, t, W1p, b1, W2p, Mp, b2, W3T, b3, out);
}